// Round 4
// baseline (69.170 us; speedup 1.0000x reference)
//
#include <hip/hip_runtime.h>

#define B 4
#define N 1024
#define K 100
#define F 42
#define H 64

#define PAIRS   (K * F)        // 4200 (k,f) pairs per atom
#define MFLT    (PAIRS * 3)    // 12600 dfeat floats per atom
#define MF4     (MFLT / 4)     // 3150 float4 per atom
#define CH_F4   768            // float4 per chunk (12 KB)
#define CH_PAIRS 1024          // pairs per chunk
#define NCH     5              // 4x1024 + 104 pairs

typedef float f32x4 __attribute__((ext_vector_type(4)));

// ---------------------------------------------------------------------------
// Kernel 1: per-atom MLP forward + analytic input gradient (1 wave / atom).
// ---------------------------------------------------------------------------
__global__ __launch_bounds__(256) void mlp_kernel(
    const float* __restrict__ image,
    const float* __restrict__ W1, const float* __restrict__ b1,
    const float* __restrict__ W2, const float* __restrict__ b2,
    const float* __restrict__ W3, const float* __restrict__ b3,
    float* __restrict__ Ei, float* __restrict__ dE)
{
    __shared__ float xsh[4][F];
    __shared__ float h1sh[4][H];
    __shared__ float aux[4][H];

    const int tid  = threadIdx.x;
    const int lane = tid & 63;
    const int wave = tid >> 6;
    const int atom = blockIdx.x * 4 + wave;

    if (lane < F) xsh[wave][lane] = image[atom * F + lane];
    __syncthreads();

    float a1 = b1[lane];
    #pragma unroll
    for (int f = 0; f < F; ++f) a1 = fmaf(xsh[wave][f], W1[f * H + lane], a1);
    const float h1 = tanhf(a1);
    h1sh[wave][lane] = h1;
    __syncthreads();

    float a2 = b2[lane];
    #pragma unroll 8
    for (int j = 0; j < H; ++j) a2 = fmaf(h1sh[wave][j], W2[j * H + lane], a2);
    const float h2 = tanhf(a2);
    const float w3 = W3[lane];

    float t = h2 * w3;
    #pragma unroll
    for (int off = 32; off > 0; off >>= 1) t += __shfl_down(t, off);
    if (lane == 0) Ei[atom] = t + b3[0];

    aux[wave][lane] = w3 * (1.0f - h2 * h2);
    __syncthreads();

    float s = 0.0f;
    #pragma unroll 8
    for (int j = 0; j < H; ++j) s = fmaf(W2[lane * H + j], aux[wave][j], s);
    const float g1 = s * (1.0f - h1 * h1);
    h1sh[wave][lane] = g1;
    __syncthreads();

    if (lane < F) {
        float dx = 0.0f;
        #pragma unroll 8
        for (int i = 0; i < H; ++i) dx = fmaf(W1[lane * H + i], h1sh[wave][i], dx);
        dE[atom * F + lane] = dx;
    }
}

// ---------------------------------------------------------------------------
// Kernel 2 (v3): Force + Etot.
// Blocks [0, B*N): one block per atom.
//   Phase A: stage neighbor ids, prefetch dfeat chunk 0 to regs, and gather
//            ALL 4200 dE values for this atom into LDS (de[k*F+f]) — the
//            streaming loop then has zero global-memory dependencies.
//   Phase B: stream dfeat in 12 KB chunks (reg-prefetch next chunk during
//            compute of current). Per chunk each thread owns 4 consecutive
//            pairs: 3x ds_read_b128 (dfeat) + 1x ds_read_b128 (de) + 12 FMA.
// Blocks [B*N, B*N+B): Etot[b] = fixed-order sum of Ei[b,:].
// ---------------------------------------------------------------------------
__global__ __launch_bounds__(256) void force_kernel(
    const float* __restrict__ dE, const float* __restrict__ dfeat,
    const int* __restrict__ neighbor, const float* __restrict__ Ei,
    float* __restrict__ force, float* __restrict__ Etot)
{
    __shared__ __align__(16) float chunkBuf[CH_F4 * 4];   // 12 KB
    __shared__ __align__(16) float deLds[PAIRS];          // 16.8 KB
    __shared__ int   nsh[K];
    __shared__ float red[4][3];

    const int tid = threadIdx.x;
    const int bid = blockIdx.x;
    const int lane = tid & 63, wave = tid >> 6;

    if (bid >= B * N) {                    // ---- Etot tail blocks ----
        const int b = bid - B * N;
        float s = 0.0f;
        for (int i = tid; i < N; i += 256) s += Ei[b * N + i];
        #pragma unroll
        for (int off = 32; off > 0; off >>= 1) s += __shfl_down(s, off);
        if (lane == 0) red[wave][0] = s;
        __syncthreads();
        if (tid == 0)
            Etot[b] = (red[0][0] + red[1][0]) + (red[2][0] + red[3][0]);
        return;
    }

    const int bn = bid;
    const int b  = bn >> 10;               // N = 1024

    if (tid < K) nsh[tid] = neighbor[bn * K + tid];
    __syncthreads();

    const f32x4* df4 = (const f32x4*)dfeat + (size_t)bn * MF4;
    const float* dEb = dE + (size_t)b * (N * F);

    // prefetch chunk 0 into regs (in flight during the de gather)
    f32x4 r0 = __builtin_nontemporal_load(&df4[tid]);
    f32x4 r1 = __builtin_nontemporal_load(&df4[256 + tid]);
    f32x4 r2 = __builtin_nontemporal_load(&df4[512 + tid]);

    // gather all dE values for this atom into LDS, indexed by pair p = k*F+f
    #pragma unroll
    for (int i = 0; i < 17; ++i) {         // 17*256 = 4352 >= 4200
        const int p = tid + 256 * i;
        if (p < PAIRS) {
            const int k  = p / F;
            const int f  = p - k * F;
            const int nb = nsh[k];
            deLds[p] = (nb > 0) ? dEb[(nb - 1) * F + f] : 0.0f;
        }
    }

    // write chunk 0
    {
        f32x4* buf = (f32x4*)chunkBuf;
        buf[tid] = r0; buf[256 + tid] = r1; buf[512 + tid] = r2;
    }
    __syncthreads();

    float fx = 0.0f, fy = 0.0f, fz = 0.0f;

    for (int c = 0; c < NCH; ++c) {
        // prefetch chunk c+1 into regs
        f32x4 s0 = {0,0,0,0}, s1 = {0,0,0,0}, s2 = {0,0,0,0};
        const bool have_next = (c + 1 < NCH);
        if (have_next) {
            const int i0 = (c + 1) * CH_F4 + tid;
            if (i0       < MF4) s0 = __builtin_nontemporal_load(&df4[i0]);
            if (i0 + 256 < MF4) s1 = __builtin_nontemporal_load(&df4[i0 + 256]);
            if (i0 + 512 < MF4) s2 = __builtin_nontemporal_load(&df4[i0 + 512]);
        }

        // compute chunk c: thread owns pairs [4*tid, 4*tid+3] within chunk
        const int npair = (c == NCH - 1) ? (PAIRS - c * CH_PAIRS) : CH_PAIRS; // 104 last
        const int p0 = 4 * tid;
        if (p0 < npair) {
            const f32x4* buf4 = (const f32x4*)chunkBuf;
            const f32x4 d0 = buf4[3 * tid + 0];   // floats 12t .. 12t+3
            const f32x4 d1 = buf4[3 * tid + 1];
            const f32x4 d2 = buf4[3 * tid + 2];
            const f32x4 e  = ((const f32x4*)deLds)[c * (CH_PAIRS / 4) + tid];
            fx = fmaf(e.x, d0.x, fx); fy = fmaf(e.x, d0.y, fy); fz = fmaf(e.x, d0.z, fz);
            fx = fmaf(e.y, d0.w, fx); fy = fmaf(e.y, d1.x, fy); fz = fmaf(e.y, d1.y, fz);
            fx = fmaf(e.z, d1.z, fx); fy = fmaf(e.z, d1.w, fy); fz = fmaf(e.z, d2.x, fz);
            fx = fmaf(e.w, d2.y, fx); fy = fmaf(e.w, d2.z, fy); fz = fmaf(e.w, d2.w, fz);
        }

        if (have_next) {
            __syncthreads();               // all reads of chunkBuf done
            f32x4* buf = (f32x4*)chunkBuf;
            buf[tid] = s0; buf[256 + tid] = s1; buf[512 + tid] = s2;
            __syncthreads();               // chunk c+1 visible
        }
    }

    #pragma unroll
    for (int off = 32; off > 0; off >>= 1) {
        fx += __shfl_down(fx, off);
        fy += __shfl_down(fy, off);
        fz += __shfl_down(fz, off);
    }
    if (lane == 0) { red[wave][0] = fx; red[wave][1] = fy; red[wave][2] = fz; }
    __syncthreads();
    if (tid == 0) {
        force[bn * 3 + 0] = (red[0][0] + red[1][0]) + (red[2][0] + red[3][0]);
        force[bn * 3 + 1] = (red[0][1] + red[1][1]) + (red[2][1] + red[3][1]);
        force[bn * 3 + 2] = (red[0][2] + red[1][2]) + (red[2][2] + red[3][2]);
    }
}

extern "C" void kernel_launch(void* const* d_in, const int* in_sizes, int n_in,
                              void* d_out, int out_size, void* d_ws, size_t ws_size,
                              hipStream_t stream)
{
    const float* image    = (const float*)d_in[0];
    const float* dfeat    = (const float*)d_in[1];
    const int*   neighbor = (const int*)d_in[2];
    // d_in[3] Egroup_weight, d_in[4] divider: unused by the reference outputs
    const float* W1 = (const float*)d_in[5];
    const float* b1 = (const float*)d_in[6];
    const float* W2 = (const float*)d_in[7];
    const float* b2 = (const float*)d_in[8];
    const float* W3 = (const float*)d_in[9];
    const float* b3 = (const float*)d_in[10];

    float* out   = (float*)d_out;
    float* Etot  = out;                 // [B]
    float* Ei    = out + B;             // [B,N]
    float* Force = out + B + B * N;     // [B,N,3]
    float* dE    = (float*)d_ws;        // [B,N,F] = 688,128 bytes

    mlp_kernel<<<(B * N) / 4, 256, 0, stream>>>(image, W1, b1, W2, b2, W3, b3, Ei, dE);
    force_kernel<<<B * N + B, 256, 0, stream>>>(dE, dfeat, neighbor, Ei, Force, Etot);
}

// Round 5
// 50.182 us; speedup vs baseline: 1.3784x; 1.3784x over previous
//
#include <hip/hip_runtime.h>

#define B 4
#define N 1024
#define K 100
#define F 42
#define H 64

// ---------------------------------------------------------------------------
// Kernel 1 (v4): per-atom MLP fwd + analytic input grad, weights in LDS.
// W1s[f][i] and W2s[j][i] stored with +1 row pad (65): both row-major reads
// (forward, W*s[r][lane]) and column-major reads (backward, W*s[lane][c])
// hit (r+c)%32-style bank patterns = 2 lanes/bank = conflict-free.
// This removes the 64-lines-per-instruction global W^T thrash.
// ---------------------------------------------------------------------------
__global__ __launch_bounds__(256) void mlp_kernel(
    const float* __restrict__ image,
    const float* __restrict__ W1, const float* __restrict__ b1,
    const float* __restrict__ W2, const float* __restrict__ b2,
    const float* __restrict__ W3, const float* __restrict__ b3,
    float* __restrict__ Ei, float* __restrict__ dE)
{
    __shared__ float W1s[F][H + 1];    // 42x65 = 10.9 KB
    __shared__ float W2s[H][H + 1];    // 64x65 = 16.6 KB
    __shared__ float xsh[4][F];
    __shared__ float h1sh[4][H];
    __shared__ float aux[4][H];

    const int tid  = threadIdx.x;
    const int lane = tid & 63;
    const int wave = tid >> 6;
    const int atom = blockIdx.x * 4 + wave;

    // cooperative coalesced staging of weights (H == 64 -> idx>>6 / idx&63)
    for (int idx = tid; idx < F * H; idx += 256)
        W1s[idx >> 6][idx & 63] = W1[idx];
    for (int idx = tid; idx < H * H; idx += 256)
        W2s[idx >> 6][idx & 63] = W2[idx];
    if (lane < F) xsh[wave][lane] = image[atom * F + lane];
    __syncthreads();

    // layer 1
    float a1 = b1[lane];
    #pragma unroll
    for (int f = 0; f < F; ++f) a1 = fmaf(xsh[wave][f], W1s[f][lane], a1);
    const float h1 = tanhf(a1);
    h1sh[wave][lane] = h1;
    __syncthreads();

    // layer 2
    float a2 = b2[lane];
    #pragma unroll 8
    for (int j = 0; j < H; ++j) a2 = fmaf(h1sh[wave][j], W2s[j][lane], a2);
    const float h2 = tanhf(a2);
    const float w3 = W3[lane];

    float t = h2 * w3;
    #pragma unroll
    for (int off = 32; off > 0; off >>= 1) t += __shfl_down(t, off);
    if (lane == 0) Ei[atom] = t + b3[0];

    aux[wave][lane] = w3 * (1.0f - h2 * h2);
    __syncthreads();

    // g1[i] = (1-h1^2) * sum_j W2[i,j] * g2[j]   (column read, LDS, pad-free)
    float s = 0.0f;
    #pragma unroll 8
    for (int j = 0; j < H; ++j) s = fmaf(W2s[lane][j], aux[wave][j], s);
    const float g1 = s * (1.0f - h1 * h1);
    h1sh[wave][lane] = g1;
    __syncthreads();

    // dE[f] = sum_i W1[f,i] * g1[i]   (row read, LDS)
    if (lane < F) {
        float dx = 0.0f;
        #pragma unroll 8
        for (int i = 0; i < H; ++i) dx = fmaf(W1s[lane][i], h1sh[wave][i], dx);
        dE[atom * F + lane] = dx;
    }
}

// ---------------------------------------------------------------------------
// Kernel 2: Force (exact R1-winner structure: direct global loads) + Etot tail.
// Blocks [0, B*N): Force[bn]. Blocks [B*N, B*N+B): Etot[b].
// ---------------------------------------------------------------------------
__global__ __launch_bounds__(256) void force_kernel(
    const float* __restrict__ dE, const float* __restrict__ dfeat,
    const int* __restrict__ neighbor, const float* __restrict__ Ei,
    float* __restrict__ force, float* __restrict__ Etot)
{
    __shared__ int   nsh[K];
    __shared__ float red[4][3];

    const int tid  = threadIdx.x;
    const int bid  = blockIdx.x;
    const int lane = tid & 63, wave = tid >> 6;

    if (bid >= B * N) {                    // ---- Etot tail blocks ----
        const int b = bid - B * N;
        float s = 0.0f;
        for (int i = tid; i < N; i += 256) s += Ei[b * N + i];
        #pragma unroll
        for (int off = 32; off > 0; off >>= 1) s += __shfl_down(s, off);
        if (lane == 0) red[wave][0] = s;
        __syncthreads();
        if (tid == 0)
            Etot[b] = (red[0][0] + red[1][0]) + (red[2][0] + red[3][0]);
        return;
    }

    const int bn = bid;
    const int b  = bn >> 10;               // N = 1024

    if (tid < K) nsh[tid] = neighbor[bn * K + tid];
    __syncthreads();

    const float* df  = dfeat + (size_t)bn * (K * F * 3);
    const float* dEb = dE + (size_t)b * (N * F);

    float fx = 0.0f, fy = 0.0f, fz = 0.0f;
    for (int p = tid; p < K * F; p += 256) {
        const int k  = p / F;
        const int f  = p - k * F;
        const int nb = nsh[k];
        const float de = (nb > 0) ? dEb[(nb - 1) * F + f] : 0.0f;
        const int base = p * 3;
        fx = fmaf(de, df[base + 0], fx);
        fy = fmaf(de, df[base + 1], fy);
        fz = fmaf(de, df[base + 2], fz);
    }

    #pragma unroll
    for (int off = 32; off > 0; off >>= 1) {
        fx += __shfl_down(fx, off);
        fy += __shfl_down(fy, off);
        fz += __shfl_down(fz, off);
    }
    if (lane == 0) { red[wave][0] = fx; red[wave][1] = fy; red[wave][2] = fz; }
    __syncthreads();
    if (tid == 0) {
        force[bn * 3 + 0] = (red[0][0] + red[1][0]) + (red[2][0] + red[3][0]);
        force[bn * 3 + 1] = (red[0][1] + red[1][1]) + (red[2][1] + red[3][1]);
        force[bn * 3 + 2] = (red[0][2] + red[1][2]) + (red[2][2] + red[3][2]);
    }
}

extern "C" void kernel_launch(void* const* d_in, const int* in_sizes, int n_in,
                              void* d_out, int out_size, void* d_ws, size_t ws_size,
                              hipStream_t stream)
{
    const float* image    = (const float*)d_in[0];
    const float* dfeat    = (const float*)d_in[1];
    const int*   neighbor = (const int*)d_in[2];
    // d_in[3] Egroup_weight, d_in[4] divider: unused by the reference outputs
    const float* W1 = (const float*)d_in[5];
    const float* b1 = (const float*)d_in[6];
    const float* W2 = (const float*)d_in[7];
    const float* b2 = (const float*)d_in[8];
    const float* W3 = (const float*)d_in[9];
    const float* b3 = (const float*)d_in[10];

    float* out   = (float*)d_out;
    float* Etot  = out;                 // [B]
    float* Ei    = out + B;             // [B,N]
    float* Force = out + B + B * N;     // [B,N,3]
    float* dE    = (float*)d_ws;        // [B,N,F]

    mlp_kernel<<<(B * N) / 4, 256, 0, stream>>>(image, W1, b1, W2, b2, W3, b3, Ei, dE);
    force_kernel<<<B * N + B, 256, 0, stream>>>(dE, dfeat, neighbor, Ei, Force, Etot);
}